// Round 2
// 1212.356 us; speedup vs baseline: 1.4536x; 1.4536x over previous
//
#include <hip/hip_runtime.h>
#include <math.h>

#define D   128
#define DE  128
#define DT  100
#define FF  10
#define BB  512
#define GG  1536
#define NN1 15360
#define NNODES 500000

constexpr int KVDIM = D + DE + DT; // 356
constexpr int QDIM  = D + DT;      // 228

typedef __attribute__((ext_vector_type(8))) short bf16x8;
typedef __attribute__((ext_vector_type(4))) float f32x4;

__device__ __forceinline__ unsigned short f2bf(float x) {
    unsigned u = __float_as_uint(x);
    u += 0x7FFFu + ((u >> 16) & 1u);
    return (unsigned short)(u >> 16);
}
__device__ __forceinline__ float bf2f(unsigned short h) {
    return __uint_as_float(((unsigned)h) << 16);
}

// ---------------------------------------------------------------------------
// Kernel 1: copy memory -> out_mem, memory_ts -> out_ts (float4 grid-stride)
// ---------------------------------------------------------------------------
__global__ void copy_kernel(const float4* __restrict__ mem,
                            const float4* __restrict__ ts,
                            float4* __restrict__ out_mem,
                            float4* __restrict__ out_ts) {
    const long nmem = (long)NNODES * D / 4;   // 16,000,000
    const long nts  = NNODES / 4;             // 125,000
    long stride = (long)gridDim.x * blockDim.x;
    for (long i = (long)blockIdx.x * blockDim.x + threadIdx.x;
         i < nmem + nts; i += stride) {
        if (i < nmem) out_mem[i] = mem[i];
        else          out_ts[i - nmem] = ts[i - nmem];
    }
}

// ---------------------------------------------------------------------------
// Kernel 2: prepack Wk|Wv (both layers) into split-bf16 MFMA B-fragment order.
// Layout per layer: hi[kc][t][lane][e] then lo[...]; 98304 shorts each.
// Element for (kc,t,lane,e): n = t*16 + (lane&15), k = kc*32 + (lane>>4)*8 + e.
// Also computes qconst[L][j] = bq[j] + sum_t cos(tb[t]) * Wq[(128+t)*128+j].
// ---------------------------------------------------------------------------
__global__ void prepack_kernel(const float* __restrict__ Wk,
                               const float* __restrict__ Wv,
                               const float* __restrict__ Wq,
                               const float* __restrict__ bq,
                               const float* __restrict__ tb,
                               short* __restrict__ bpack,
                               float* __restrict__ qc_ws) {
    int gid = blockIdx.x * 256 + threadIdx.x;
    if (gid < 2 * 98304) {
        int L = gid / 98304;
        int rem = gid - L * 98304;
        int e  = rem & 7;
        int l  = (rem >> 3) & 63;
        int t  = (rem >> 9) & 15;
        int kc = rem >> 13;
        int n = t * 16 + (l & 15);
        int k = kc * 32 + (l >> 4) * 8 + e;
        float v = 0.f;
        if (k < KVDIM) {
            const float* Wb = (n < D) ? (Wk + (long)L * KVDIM * D)
                                      : (Wv + (long)L * KVDIM * D);
            int nn = (n < D) ? n : (n - D);
            v = Wb[(long)k * D + nn];
        }
        unsigned short hi = f2bf(v);
        unsigned short lo = f2bf(v - bf2f(hi));
        bpack[(long)L * 196608 + rem]         = (short)hi;
        bpack[(long)L * 196608 + 98304 + rem] = (short)lo;
    } else if (gid < 2 * 98304 + 256) {
        int x = gid - 2 * 98304;
        int L = x >> 7, j = x & 127;
        float s = bq[L * D + j];
        for (int t = 0; t < DT; ++t)
            s += cosf(tb[L * DT + t]) * Wq[(long)L * QDIM * D + (D + t) * D + j];
        qc_ws[L * D + j] = s;
    }
}

// ---------------------------------------------------------------------------
// Kernel 3: MFMA attention core.  3 dst rows/block (30 kv rows, padded to 32),
// 256 threads = 4 waves.  Fuses: dh gather, q projection, split-bf16 (hi+lo)
// K/V projection via mfma_f32_16x16x32_bf16 (3 MFMAs/tile ~ fp32 accuracy),
// scores/softmax/PV in fp32 from LDS.  Writes o (pre-Wo attn output) to o_ws;
// o_ws rows are block-private so it may alias a buffer later read per-row.
// LDS: A 50,176 B (aliased by K/V fp32 post-GEMM) + dh 1536 + q 1536 + sc 240.
// ---------------------------------------------------------------------------
#define AS 392          // A row stride in shorts (bank-spread padding)
#define ATTN_SMEM (50176 + 1536 + 1536 + 240)

__global__ __launch_bounds__(256, 3) void attn_mfma_kernel(
    const float* __restrict__ dst_feat,   // N x D
    const int*   __restrict__ dst_nodes,  // N
    const float* __restrict__ src_feat,   // N x F x D
    const int*   __restrict__ src_nodes,  // N x F
    const float* __restrict__ dst_ts,     // N
    const float* __restrict__ src_ts,     // N x F
    const float* __restrict__ edge_feat,  // N x F x DE
    const float* __restrict__ memory,     // NNODES x D
    const float* __restrict__ tw, const float* __restrict__ tb,
    const float* __restrict__ bk, const float* __restrict__ bv,
    const float* __restrict__ Wq,         // this layer's 228x128 (rows 0..127)
    const float* __restrict__ qc,         // this layer's qconst (128)
    const short* __restrict__ bpack,      // this layer's packed Wk|Wv split
    float* __restrict__ o_ws)             // N x D (attention output)
{
    __shared__ __align__(16) char smem[ATTN_SMEM];
    short* A_hi  = (short*)smem;                  // [32][AS]
    short* A_lo  = A_hi + 32 * AS;                // [32][AS]
    float* K_lds = (float*)smem;                  // [30][132] (aliases A)
    float* V_lds = K_lds + 30 * 132;              // [30][132]
    float* dh_lds = (float*)(smem + 50176);       // [3][128]
    float* q_lds  = (float*)(smem + 50176 + 1536);// [3][128]
    float* sc     = (float*)(smem + 50176 + 3072);// [3][2][10]

    const int tid = threadIdx.x;
    const int base = blockIdx.x * 3;

    // phase 1: zero A (pad rows 30-31, pad cols 356.. must be 0) + gather dh
    {
        int4 z = {0, 0, 0, 0};
        int4* az = (int4*)smem;
        for (int i = tid; i < 50176 / 16; i += 256) az[i] = z;
    }
    for (int idx = tid; idx < 3 * D; idx += 256) {
        int r = idx >> 7, c = idx & 127;
        long row = base + r;
        dh_lds[idx] = dst_feat[row * D + c] +
                      memory[(long)dst_nodes[row] * D + c];
    }
    __syncthreads();

    // phase 2a: build kv tile as split bf16 (rows 0..29, cols 0..355)
    for (int idx = tid; idx < 30 * KVDIM; idx += 256) {
        int r = idx / KVDIM;
        int c = idx - r * KVDIM;
        int row = base + r / FF;
        int f = r - (r / FF) * FF;
        long rf = (long)row * FF + f;
        float val;
        if (c < D) {
            val = src_feat[rf * D + c] + memory[(long)src_nodes[rf] * D + c];
        } else if (c < D + DE) {
            val = edge_feat[rf * DE + (c - D)];
        } else {
            int tc = c - (D + DE);
            float dt_ = dst_ts[row] - src_ts[rf];
            val = cosf(dt_ * tw[tc] + tb[tc]);
        }
        unsigned short hi = f2bf(val);
        A_hi[r * AS + c] = (short)hi;
        A_lo[r * AS + c] = (short)f2bf(val - bf2f(hi));
    }
    // phase 2b: q = dh @ Wq[0:128] + qconst (dh_lds ready after barrier)
    for (int idx = tid; idx < 3 * D; idx += 256) {
        int row = idx >> 7, j = idx & 127;
        float s = qc[j];
        for (int c = 0; c < D; ++c) s += dh_lds[row * D + c] * Wq[c * D + j];
        q_lds[idx] = s;
    }
    __syncthreads();

    // GEMM: [32 x 384] x [384 x 256] -> K|V, split-bf16 3-term emulation
    const int l = tid & 63;
    const int w = tid >> 6;        // wave id: owns output cols [w*64, w*64+64)
    const int arow = l & 15;
    const int kgrp = l >> 4;

    f32x4 acc[2][4] = {};
    const bf16x8* bpv = (const bf16x8*)bpack;

    for (int kc = 0; kc < 12; ++kc) {
        bf16x8 bh[4], bl[4];
        const bf16x8* bp = bpv + ((kc * 16 + w * 4) * 64 + l);
        #pragma unroll
        for (int t = 0; t < 4; ++t) {
            bh[t] = bp[t * 64];
            bl[t] = bp[t * 64 + 12288];   // lo matrix offset: 98304 shorts
        }
        bf16x8 ah[2], al[2];
        #pragma unroll
        for (int mt = 0; mt < 2; ++mt) {
            const short* pa = A_hi + (mt * 16 + arow) * AS + kc * 32 + kgrp * 8;
            ah[mt] = *(const bf16x8*)pa;
            al[mt] = *(const bf16x8*)(pa + 32 * AS);
        }
        #pragma unroll
        for (int mt = 0; mt < 2; ++mt)
            #pragma unroll
            for (int t = 0; t < 4; ++t) {
                acc[mt][t] = __builtin_amdgcn_mfma_f32_16x16x32_bf16(ah[mt], bh[t], acc[mt][t], 0, 0, 0);
                acc[mt][t] = __builtin_amdgcn_mfma_f32_16x16x32_bf16(ah[mt], bl[t], acc[mt][t], 0, 0, 0);
                acc[mt][t] = __builtin_amdgcn_mfma_f32_16x16x32_bf16(al[mt], bh[t], acc[mt][t], 0, 0, 0);
            }
    }
    __syncthreads();   // all A reads complete; safe to alias with K/V

    // scatter accumulators to K/V LDS (+bias).  C/D: col=lane&15, row=(lane>>4)*4+reg
    #pragma unroll
    for (int mt = 0; mt < 2; ++mt) {
        #pragma unroll
        for (int t = 0; t < 4; ++t) {
            int col = (w * 4 + t) * 16 + arow;
            #pragma unroll
            for (int r = 0; r < 4; ++r) {
                int row = mt * 16 + kgrp * 4 + r;
                if (row < 30) {
                    float v = acc[mt][t][r];
                    if (col < D) K_lds[row * 132 + col]       = v + bk[col];
                    else         V_lds[row * 132 + (col - D)] = v + bv[col - D];
                }
            }
        }
    }
    __syncthreads();

    // scores: 60 (row,f,h) dots of 64
    if (tid < 60) {
        int row = tid / 20;
        int rem = tid - row * 20;
        int f = rem >> 1, h = rem & 1;
        const float* qp = q_lds + row * D + h * 64;
        const float* kp = K_lds + (row * FF + f) * 132 + h * 64;
        float s = 0.f;
        #pragma unroll
        for (int d = 0; d < 64; d += 4) {
            float4 qv = *(const float4*)(qp + d);
            float4 kv = *(const float4*)(kp + d);
            s += qv.x * kv.x + qv.y * kv.y + qv.z * kv.z + qv.w * kv.w;
        }
        sc[(row * 2 + h) * FF + f] = s * 0.125f;
    }
    __syncthreads();
    if (tid < 6) {
        int r = tid >> 1, h = tid & 1;
        float* sp = sc + (r * 2 + h) * FF;
        float m = -1e30f;
        #pragma unroll
        for (int f = 0; f < FF; ++f) m = fmaxf(m, sp[f]);
        float sum = 0.f;
        #pragma unroll
        for (int f = 0; f < FF; ++f) { float e = expf(sp[f] - m); sp[f] = e; sum += e; }
        float inv = 1.f / sum;
        #pragma unroll
        for (int f = 0; f < FF; ++f) sp[f] *= inv;
    }
    __syncthreads();

    // PV: o[row][j] = sum_f a[row][h(j)][f] * V[row*10+f][j]
    for (int idx = tid; idx < 3 * D; idx += 256) {
        int row = idx >> 7, j = idx & 127;
        int h = j >> 6;
        const float* ap = sc + (row * 2 + h) * FF;
        float o = 0.f;
        #pragma unroll
        for (int f = 0; f < FF; ++f) o += ap[f] * V_lds[(row * FF + f) * 132 + j];
        o_ws[(long)(base + row) * D + j] = o;
    }
}

// ---------------------------------------------------------------------------
// Kernel 4: output projection: out = relu([dh|o] @ Wo + bo), optional
// (x + add_in) * 0.5.  dh recomputed (cheap gather).  o_in may equal out:
// each block reads its own 4 rows into LDS before writing them.
// ---------------------------------------------------------------------------
__global__ __launch_bounds__(256) void wo_kernel(
    const float* __restrict__ dst_feat, const int* __restrict__ dst_nodes,
    const float* __restrict__ memory,
    const float* __restrict__ o_in,
    const float* __restrict__ Wo, const float* __restrict__ bo,
    const float* __restrict__ add_in, float* __restrict__ out)
{
    __shared__ float dh[4][D], oo[4][D];
    const int tid = threadIdx.x, j = tid & 127, rg = tid >> 7;
    const int base = blockIdx.x * 4;
    for (int idx = tid; idx < 4 * D; idx += 256) {
        int r = idx >> 7, c = idx & 127;
        long row = base + r;
        dh[r][c] = dst_feat[row * D + c] + memory[(long)dst_nodes[row] * D + c];
        oo[r][c] = o_in[row * D + c];
    }
    __syncthreads();
    const int r0 = rg * 2;
    float a0 = bo[j], a1 = bo[j];
    for (int c = 0; c < D; ++c) {
        float wv = Wo[c * D + j];
        a0 += dh[r0][c] * wv;
        a1 += dh[r0 + 1][c] * wv;
    }
    for (int c = 0; c < D; ++c) {
        float wv = Wo[(D + c) * D + j];
        a0 += oo[r0][c] * wv;
        a1 += oo[r0 + 1][c] * wv;
    }
    long row = base + r0;
    float v0 = fmaxf(a0, 0.f), v1 = fmaxf(a1, 0.f);
    if (add_in) {
        v0 = (v0 + add_in[row * D + j]) * 0.5f;
        v1 = (v1 + add_in[(row + 1) * D + j]) * 0.5f;
    }
    out[row * D + j]       = v0;
    out[(row + 1) * D + j] = v1;
}

// ---------------------------------------------------------------------------
// Fallback scalar attention (verbatim from the verified 1774 us pipeline).
// Used only when ws_size cannot hold bpack/qc.
// ---------------------------------------------------------------------------
__global__ __launch_bounds__(256) void attn_fallback_kernel(
    int N,
    const float* __restrict__ dst_feat,
    const float* __restrict__ src_feat,
    const int*   __restrict__ dst_nodes,
    const int*   __restrict__ src_nodes,
    const float* __restrict__ dst_ts,
    const float* __restrict__ src_ts,
    const float* __restrict__ edge_feat,
    const float* __restrict__ memory,
    const float* __restrict__ Wq, const float* __restrict__ bq,
    const float* __restrict__ Wk, const float* __restrict__ bk,
    const float* __restrict__ Wv, const float* __restrict__ bv,
    const float* __restrict__ Wo, const float* __restrict__ bo,
    const float* __restrict__ tw, const float* __restrict__ tb,
    const float* __restrict__ add_in,
    float* __restrict__ out)
{
    __shared__ float kv_lds[4 * FF * KVDIM];
    __shared__ float dh_lds[4][D];
    __shared__ float qt_lds[DT];
    __shared__ float sc_lds[4][2][FF];
    __shared__ float o_lds[4][D];

    const int tid  = threadIdx.x;
    const int j    = tid & 127;
    const int rg   = tid >> 7;
    const int base = blockIdx.x * 4;
    const int head = j >> 6;

    if (tid < DT) qt_lds[tid] = cosf(tb[tid]);

    for (int idx = tid; idx < 4 * D; idx += 256) {
        int r = idx >> 7, c = idx & 127;
        int row = base + r;
        if (row < N)
            dh_lds[r][c] = dst_feat[(long)row * D + c] +
                           memory[(long)dst_nodes[row] * D + c];
    }
    for (int idx = tid; idx < 4 * FF * KVDIM; idx += 256) {
        int r   = idx / (FF * KVDIM);
        int rem = idx - r * (FF * KVDIM);
        int f   = rem / KVDIM;
        int c   = rem - f * KVDIM;
        int row = base + r;
        if (row >= N) continue;
        float val;
        if (c < D) {
            val = src_feat[((long)row * FF + f) * D + c] +
                  memory[(long)src_nodes[row * FF + f] * D + c];
        } else if (c < D + DE) {
            val = edge_feat[((long)row * FF + f) * DE + (c - D)];
        } else {
            float dt_ = dst_ts[row] - src_ts[row * FF + f];
            int tc = c - (D + DE);
            val = cosf(dt_ * tw[tc] + tb[tc]);
        }
        kv_lds[idx] = val;
    }
    __syncthreads();

    const int r0 = rg * 2;
    float q0 = bq[j], q1 = bq[j];
    for (int c = 0; c < D; ++c) {
        float wq = Wq[c * D + j];
        q0 += dh_lds[r0][c] * wq;
        q1 += dh_lds[r0 + 1][c] * wq;
    }
    {
        float qadd = 0.f;
        for (int c = 0; c < DT; ++c) qadd += qt_lds[c] * Wq[(D + c) * D + j];
        q0 += qadd; q1 += qadd;
    }

    float acc_k[2][FF], acc_v[2][FF];
    #pragma unroll
    for (int r2 = 0; r2 < 2; ++r2)
        #pragma unroll
        for (int f = 0; f < FF; ++f) { acc_k[r2][f] = 0.f; acc_v[r2][f] = 0.f; }

    for (int c = 0; c < KVDIM; c += 4) {
        float wk0 = Wk[(c + 0) * D + j], wk1 = Wk[(c + 1) * D + j];
        float wk2 = Wk[(c + 2) * D + j], wk3 = Wk[(c + 3) * D + j];
        float wv0 = Wv[(c + 0) * D + j], wv1 = Wv[(c + 1) * D + j];
        float wv2 = Wv[(c + 2) * D + j], wv3 = Wv[(c + 3) * D + j];
        #pragma unroll
        for (int r2 = 0; r2 < 2; ++r2) {
            #pragma unroll
            for (int f = 0; f < FF; ++f) {
                const float4 kvv = *(const float4*)&kv_lds[((r0 + r2) * FF + f) * KVDIM + c];
                acc_k[r2][f] += kvv.x * wk0 + kvv.y * wk1 + kvv.z * wk2 + kvv.w * wk3;
                acc_v[r2][f] += kvv.x * wv0 + kvv.y * wv1 + kvv.z * wv2 + kvv.w * wv3;
            }
        }
    }

    const float bkj = bk[j], bvj = bv[j];
    const float qv[2] = {q0, q1};

    #pragma unroll
    for (int r2 = 0; r2 < 2; ++r2) {
        #pragma unroll
        for (int f = 0; f < FF; ++f) {
            float val = qv[r2] * (acc_k[r2][f] + bkj);
            for (int off = 32; off > 0; off >>= 1) val += __shfl_xor(val, off, 64);
            if ((tid & 63) == 0) sc_lds[r0 + r2][head][f] = val;
        }
    }
    __syncthreads();

    if (tid < 8) {
        int r = tid >> 1, h = tid & 1;
        float s[FF], m = -1e30f;
        #pragma unroll
        for (int f = 0; f < FF; ++f) { s[f] = sc_lds[r][h][f] * 0.125f; m = fmaxf(m, s[f]); }
        float sum = 0.f;
        #pragma unroll
        for (int f = 0; f < FF; ++f) { s[f] = expf(s[f] - m); sum += s[f]; }
        float inv = 1.f / sum;
        #pragma unroll
        for (int f = 0; f < FF; ++f) sc_lds[r][h][f] = s[f] * inv;
    }
    __syncthreads();

    #pragma unroll
    for (int r2 = 0; r2 < 2; ++r2) {
        float o = 0.f;
        #pragma unroll
        for (int f = 0; f < FF; ++f) o += sc_lds[r0 + r2][head][f] * (acc_v[r2][f] + bvj);
        o_lds[r0 + r2][j] = o;
    }
    __syncthreads();

    float a0 = bo[j], a1 = bo[j];
    for (int c = 0; c < D; ++c) {
        float w = Wo[c * D + j];
        a0 += dh_lds[r0][c] * w;
        a1 += dh_lds[r0 + 1][c] * w;
    }
    for (int c = 0; c < D; ++c) {
        float w = Wo[(D + c) * D + j];
        a0 += o_lds[r0][c] * w;
        a1 += o_lds[r0 + 1][c] * w;
    }
    {
        int row = base + r0;
        if (row < N) {
            float v = fmaxf(a0, 0.f);
            if (add_in) v = (v + add_in[(long)row * D + j]) * 0.5f;
            out[(long)row * D + j] = v;
        }
        row = base + r0 + 1;
        if (row < N) {
            float v = fmaxf(a1, 0.f);
            if (add_in) v = (v + add_in[(long)row * D + j]) * 0.5f;
            out[(long)row * D + j] = v;
        }
    }
}

// ---------------------------------------------------------------------------
// Kernel: h_root1[g,d] = mean_f h1[g*10+f, d]   (must run BEFORE e2n)
// ---------------------------------------------------------------------------
__global__ void hroot_kernel(const float* __restrict__ h1, float* __restrict__ out) {
    int idx = blockIdx.x * blockDim.x + threadIdx.x;
    if (idx >= GG * D) return;
    int g = idx >> 7, d = idx & 127;
    float s = 0.f;
    #pragma unroll
    for (int f = 0; f < FF; ++f) s += h1[(long)(g * FF + f) * D + d];
    out[idx] = s / 10.0f;
}

// ---------------------------------------------------------------------------
// Kernel: next_src = h1 @ e2n_W + e2n_b   (in-place on h1: row-independent)
// ---------------------------------------------------------------------------
__global__ __launch_bounds__(256) void e2n_kernel(
    float* __restrict__ h1, const float* __restrict__ W, const float* __restrict__ b) {
    __shared__ float h_lds[4][D];
    const int tid = threadIdx.x, j = tid & 127, rg = tid >> 7;
    const int base = blockIdx.x * 4;
    for (int idx = tid; idx < 4 * D; idx += 256)
        h_lds[idx >> 7][idx & 127] = h1[(long)(base + (idx >> 7)) * D + (idx & 127)];
    __syncthreads();
    float a0 = b[j], a1 = b[j];
    const int r0 = rg * 2;
    for (int c = 0; c < D; ++c) {
        float w = W[c * D + j];
        a0 += h_lds[r0][c] * w;
        a1 += h_lds[r0 + 1][c] * w;
    }
    h1[(long)(base + r0) * D + j]     = a0;
    h1[(long)(base + r0 + 1) * D + j] = a1;
}

// ---------------------------------------------------------------------------
// Kernel: GRU memory update (1024 rows), 2 rows/block, 384 threads
// ---------------------------------------------------------------------------
__global__ __launch_bounds__(384) void gru_kernel(
    const int*   __restrict__ dst_nodes0,
    const float* __restrict__ root_ts,
    const float* __restrict__ root_edge_feat,
    const float* __restrict__ memory,
    const float* __restrict__ memory_ts,
    const float* __restrict__ h_total,
    const float* __restrict__ mt_w, const float* __restrict__ mt_b,
    const float* __restrict__ Wih,  const float* __restrict__ Whh,
    const float* __restrict__ bih,  const float* __restrict__ bhh,
    float* __restrict__ new_mem)
{
    __shared__ float x_lds[2][484];
    __shared__ float gi_lds[2][384];
    __shared__ float gh_lds[2][384];
    const int tid = threadIdx.x;
    const int base = blockIdx.x * 2;

    for (int idx = tid; idx < 2 * 484; idx += 384) {
        int r = idx / 484, c = idx - r * 484;
        int row = base + r;
        int node = dst_nodes0[row];
        float v;
        if (c < 128)      v = h_total[(long)row * D + c];
        else if (c < 256) v = memory[(long)node * D + (c - 128)];
        else if (c < 356) {
            float dt_ = fmaxf(root_ts[row & 511] - memory_ts[node], 0.f);
            v = cosf(dt_ * mt_w[c - 256] + mt_b[c - 256]);
        } else            v = root_edge_feat[(long)(row & 511) * DE + (c - 356)];
        x_lds[r][c] = v;
    }
    __syncthreads();

    {
        float g0 = bih[tid], g1 = bih[tid];
        for (int c = 0; c < 484; ++c) {
            float w = Wih[c * 384 + tid];
            g0 += x_lds[0][c] * w;
            g1 += x_lds[1][c] * w;
        }
        gi_lds[0][tid] = g0; gi_lds[1][tid] = g1;
        float h0 = bhh[tid], h1_ = bhh[tid];
        for (int c = 0; c < 128; ++c) {
            float w = Whh[c * 384 + tid];
            h0  += x_lds[0][128 + c] * w;
            h1_ += x_lds[1][128 + c] * w;
        }
        gh_lds[0][tid] = h0; gh_lds[1][tid] = h1_;
    }
    __syncthreads();

    if (tid < 256) {
        int r = tid >> 7, d = tid & 127;
        float ir = gi_lds[r][d], iz = gi_lds[r][128 + d], in_ = gi_lds[r][256 + d];
        float hr = gh_lds[r][d], hz = gh_lds[r][128 + d], hn  = gh_lds[r][256 + d];
        float rr = 1.f / (1.f + expf(-(ir + hr)));
        float zz = 1.f / (1.f + expf(-(iz + hz)));
        float nn = tanhf(in_ + rr * hn);
        float h  = x_lds[r][128 + d];
        new_mem[(long)(base + r) * D + d] = (1.f - zz) * nn + zz * h;
    }
}

// ---------------------------------------------------------------------------
// Kernel: scatter new_mem into out_mem with last-occurrence-wins
// ---------------------------------------------------------------------------
__global__ __launch_bounds__(128) void scatter_kernel(
    const int*   __restrict__ dst_nodes0,
    const float* __restrict__ root_ts,
    const float* __restrict__ new_mem,
    float* __restrict__ out_mem,
    float* __restrict__ out_ts)
{
    __shared__ int lose;
    const int i = blockIdx.x;     // 0..1023
    const int tid = threadIdx.x;
    if (tid == 0) lose = 0;
    __syncthreads();
    const int node = dst_nodes0[i];
    for (int jj = i + 1 + tid; jj < 1024; jj += 128)
        if (dst_nodes0[jj] == node) lose = 1;
    __syncthreads();
    if (!lose) {
        out_mem[(long)node * D + tid] = new_mem[(long)i * D + tid];
        if (tid == 0) out_ts[node] = root_ts[i & 511];
    }
}

// ---------------------------------------------------------------------------
// Kernel: edge predictor, 4 rows/block, 128 threads
// ---------------------------------------------------------------------------
__global__ __launch_bounds__(128) void ep_kernel(
    const float* __restrict__ h_total,
    const float* __restrict__ Wsrc, const float* __restrict__ bsrc,
    const float* __restrict__ Wdst, const float* __restrict__ bdst,
    const float* __restrict__ Wout, const float* __restrict__ bout,
    float* __restrict__ out_pos, float* __restrict__ out_neg)
{
    __shared__ float hs[4][D], hd[4][D], hn[4][D];
    __shared__ float part[4][2][2];
    const int tid = threadIdx.x;
    const int base = blockIdx.x * 4;
    for (int idx = tid; idx < 4 * D; idx += 128) {
        int r = idx >> 7, c = idx & 127;
        hs[r][c] = h_total[(long)(base + r) * D + c];
        hd[r][c] = h_total[(long)(512 + base + r) * D + c];
        hn[r][c] = h_total[(long)(1024 + base + r) * D + c];
    }
    __syncthreads();
    const int j = tid;
    const float wout = Wout[j];
    for (int r = 0; r < 4; ++r) {
        float s = bsrc[j], dp = bdst[j], dn = bdst[j];
        for (int c = 0; c < D; ++c) {
            float ws = Wsrc[c * D + j], wd = Wdst[c * D + j];
            s  += hs[r][c] * ws;
            dp += hd[r][c] * wd;
            dn += hn[r][c] * wd;
        }
        float pv = fmaxf(s + dp, 0.f) * wout;
        float nv = fmaxf(s + dn, 0.f) * wout;
        for (int off = 32; off > 0; off >>= 1) {
            pv += __shfl_xor(pv, off, 64);
            nv += __shfl_xor(nv, off, 64);
        }
        if ((tid & 63) == 0) { part[r][0][tid >> 6] = pv; part[r][1][tid >> 6] = nv; }
    }
    __syncthreads();
    if (tid < 4) {
        out_pos[base + tid] = part[tid][0][0] + part[tid][0][1] + bout[0];
        out_neg[base + tid] = part[tid][1][0] + part[tid][1][1] + bout[0];
    }
}

// ---------------------------------------------------------------------------
extern "C" void kernel_launch(void* const* d_in, const int* in_sizes, int n_in,
                              void* d_out, int out_size, void* d_ws, size_t ws_size,
                              hipStream_t stream) {
    const int*   dst_nodes0     = (const int*)d_in[0];
    const int*   src_nodes0     = (const int*)d_in[1];
    const float* dst_feat0      = (const float*)d_in[2];
    const float* dst_ts0        = (const float*)d_in[3];
    const float* src_ts0        = (const float*)d_in[4];
    const float* edge_feat0     = (const float*)d_in[5];
    const int*   dst_nodes1     = (const int*)d_in[6];
    const int*   src_nodes1     = (const int*)d_in[7];
    const float* dst_feat1      = (const float*)d_in[8];
    const float* src_feat1      = (const float*)d_in[9];
    const float* dst_ts1        = (const float*)d_in[10];
    const float* src_ts1        = (const float*)d_in[11];
    const float* edge_feat1     = (const float*)d_in[12];
    const float* root_ts        = (const float*)d_in[13];
    const float* root_edge_feat = (const float*)d_in[14];
    const float* memory         = (const float*)d_in[15];
    const float* memory_ts      = (const float*)d_in[16];
    const float* Wq  = (const float*)d_in[17];
    const float* bq  = (const float*)d_in[18];
    const float* Wk  = (const float*)d_in[19];
    const float* bk  = (const float*)d_in[20];
    const float* Wv  = (const float*)d_in[21];
    const float* bv  = (const float*)d_in[22];
    const float* Wo  = (const float*)d_in[23];
    const float* bo  = (const float*)d_in[24];
    const float* tw  = (const float*)d_in[25];
    const float* tb  = (const float*)d_in[26];
    const float* e2n_W = (const float*)d_in[27];
    const float* e2n_b = (const float*)d_in[28];
    const float* mt_w  = (const float*)d_in[29];
    const float* mt_b  = (const float*)d_in[30];
    const float* gru_Wih = (const float*)d_in[31];
    const float* gru_Whh = (const float*)d_in[32];
    const float* gru_bih = (const float*)d_in[33];
    const float* gru_bhh = (const float*)d_in[34];
    const float* ep_Wsrc = (const float*)d_in[35];
    const float* ep_bsrc = (const float*)d_in[36];
    const float* ep_Wdst = (const float*)d_in[37];
    const float* ep_bdst = (const float*)d_in[38];
    const float* ep_Wout = (const float*)d_in[39];
    const float* ep_bout = (const float*)d_in[40];

    float* out     = (float*)d_out;
    float* out_pos = out;
    float* out_neg = out + 512;
    float* out_mem = out + 1024;
    float* out_ts  = out + 1024 + (long)NNODES * D;

    float* ws       = (float*)d_ws;
    float* h1       = ws;                          // NN1*D
    float* h_root1  = h1 + (long)NN1 * D;          // GG*D
    float* h_total  = h_root1 + (long)GG * D;      // GG*D
    float* new_mem  = h_total + (long)GG * D;      // 1024*D
    float* qc_ws    = new_mem + 1024L * D;         // 2*D
    short* bpack    = (short*)(qc_ws + 256);       // 2*196608 shorts (786,432 B)

    // bytes needed by the MFMA path:
    //   (NN1+2*GG+1024)*D + 256 floats  +  786,432 B  = 10,748,928 B
    const size_t REQ_MFMA = (size_t)((long)(NN1 + 2 * GG + 1024) * D + 256) * 4
                          + 2 * 196608 * sizeof(short);
    const bool use_mfma = (ws_size == 0) || (ws_size >= REQ_MFMA);

    // 1. bulk copy memory/memory_ts -> out (scatter overwrites updated rows)
    copy_kernel<<<4096, 256, 0, stream>>>((const float4*)memory, (const float4*)memory_ts,
                                          (float4*)out_mem, (float4*)out_ts);

    if (use_mfma) {
        // 2. prepack split-bf16 weights (both layers) + qconst
        prepack_kernel<<<769, 256, 0, stream>>>(Wk, Wv, Wq, bq, tb, bpack, qc_ws);
        // 3. layer-1 attention core (MFMA) -> o into h1 (block-private rows)
        attn_mfma_kernel<<<NN1 / 3, 256, 0, stream>>>(
            dst_feat1, dst_nodes1, src_feat1, src_nodes1, dst_ts1, src_ts1, edge_feat1,
            memory, tw + DT, tb + DT, bk + D, bv + D,
            Wq + QDIM * D, qc_ws + D, bpack + 196608, h1);
        // 4. layer-1 output projection, in-place on h1
        wo_kernel<<<NN1 / 4, 256, 0, stream>>>(dst_feat1, dst_nodes1, memory,
                                               h1, Wo + 2 * D * D, bo + D, nullptr, h1);
        // 5. h_root1 (before e2n clobbers h1)
        hroot_kernel<<<(GG * D + 255) / 256, 256, 0, stream>>>(h1, h_root1);
        // 6. next_src = h1 @ e2n_W + b, in-place
        e2n_kernel<<<NN1 / 4, 256, 0, stream>>>(h1, e2n_W, e2n_b);
        // 7. layer-0 attention core (MFMA) -> o into h_total
        attn_mfma_kernel<<<GG / 3, 256, 0, stream>>>(
            dst_feat0, dst_nodes0, h1, src_nodes0, dst_ts0, src_ts0, edge_feat0,
            memory, tw, tb, bk, bv,
            Wq, qc_ws, bpack, h_total);
        // 8. layer-0 output projection, in-place on h_total, fused (x+h_root1)/2
        wo_kernel<<<GG / 4, 256, 0, stream>>>(dst_feat0, dst_nodes0, memory,
                                              h_total, Wo, bo, h_root1, h_total);
    } else {
        // Fallback: verified scalar pipeline (fits in 9,961,472 B)
        attn_fallback_kernel<<<NN1 / 4, 256, 0, stream>>>(
            NN1, dst_feat1, src_feat1, dst_nodes1, src_nodes1, dst_ts1, src_ts1,
            edge_feat1, memory,
            Wq + QDIM * D, bq + D, Wk + KVDIM * D, bk + D, Wv + KVDIM * D, bv + D,
            Wo + 2 * D * D, bo + D, tw + DT, tb + DT, nullptr, h1);
        hroot_kernel<<<(GG * D + 255) / 256, 256, 0, stream>>>(h1, h_root1);
        e2n_kernel<<<NN1 / 4, 256, 0, stream>>>(h1, e2n_W, e2n_b);
        attn_fallback_kernel<<<GG / 4, 256, 0, stream>>>(
            GG, dst_feat0, h1, dst_nodes0, src_nodes0, dst_ts0, src_ts0, edge_feat0,
            memory, Wq, bq, Wk, bk, Wv, bv, Wo, bo, tw, tb, h_root1, h_total);
    }

    // 9. GRU memory update
    gru_kernel<<<512, 384, 0, stream>>>(dst_nodes0, root_ts, root_edge_feat, memory,
                                        memory_ts, h_total, mt_w, mt_b,
                                        gru_Wih, gru_Whh, gru_bih, gru_bhh, new_mem);
    // 10. scatter (last-occurrence-wins)
    scatter_kernel<<<1024, 128, 0, stream>>>(dst_nodes0, root_ts, new_mem, out_mem, out_ts);
    // 11. edge predictor
    ep_kernel<<<BB / 4, 128, 0, stream>>>(h_total, ep_Wsrc, ep_bsrc, ep_Wdst, ep_bdst,
                                          ep_Wout, ep_bout, out_pos, out_neg);
}

// Round 3
// 1000.021 us; speedup vs baseline: 1.7623x; 1.2123x over previous
//
#include <hip/hip_runtime.h>
#include <math.h>

#define D   128
#define DE  128
#define DT  100
#define FF  10
#define BB  512
#define GG  1536
#define NN1 15360
#define NNODES 500000

constexpr int KVDIM = D + DE + DT; // 356
constexpr int QDIM  = D + DT;      // 228

typedef __attribute__((ext_vector_type(8))) short bf16x8;
typedef __attribute__((ext_vector_type(4))) float f32x4;

__device__ __forceinline__ unsigned short f2bf(float x) {
    unsigned u = __float_as_uint(x);
    u += 0x7FFFu + ((u >> 16) & 1u);
    return (unsigned short)(u >> 16);
}
__device__ __forceinline__ float bf2f(unsigned short h) {
    return __uint_as_float(((unsigned)h) << 16);
}

// ---------------------------------------------------------------------------
// Kernel 1: copy memory -> out_mem, memory_ts -> out_ts (float4 grid-stride)
// ---------------------------------------------------------------------------
__global__ void copy_kernel(const float4* __restrict__ mem,
                            const float4* __restrict__ ts,
                            float4* __restrict__ out_mem,
                            float4* __restrict__ out_ts) {
    const long nmem = (long)NNODES * D / 4;   // 16,000,000
    const long nts  = NNODES / 4;             // 125,000
    long stride = (long)gridDim.x * blockDim.x;
    for (long i = (long)blockIdx.x * blockDim.x + threadIdx.x;
         i < nmem + nts; i += stride) {
        if (i < nmem) out_mem[i] = mem[i];
        else          out_ts[i - nmem] = ts[i - nmem];
    }
}

// ---------------------------------------------------------------------------
// Kernel 2: prepack Wk|Wv (both layers) into split-bf16 MFMA B-fragment order.
// Layout per layer: hi[kc][t][lane][e] then lo[...]; 98304 shorts each.
// Element for (kc,t,lane,e): n = t*16 + (lane&15), k = kc*32 + (lane>>4)*8 + e.
// k==356 row carries the bias (bk|bv) -- A supplies a constant-1 column there.
// Also computes qconst[L][j] = bq[j] + sum_t cos(tb[t]) * Wq[(128+t)*128+j].
// ---------------------------------------------------------------------------
__global__ void prepack_kernel(const float* __restrict__ Wk,
                               const float* __restrict__ Wv,
                               const float* __restrict__ Wq,
                               const float* __restrict__ bq,
                               const float* __restrict__ bk,
                               const float* __restrict__ bv,
                               const float* __restrict__ tb,
                               short* __restrict__ bpack,
                               float* __restrict__ qc_ws) {
    int gid = blockIdx.x * 256 + threadIdx.x;
    if (gid < 2 * 98304) {
        int L = gid / 98304;
        int rem = gid - L * 98304;
        int e  = rem & 7;
        int l  = (rem >> 3) & 63;
        int t  = (rem >> 9) & 15;
        int kc = rem >> 13;
        int n = t * 16 + (l & 15);
        int k = kc * 32 + (l >> 4) * 8 + e;
        float v = 0.f;
        if (k < KVDIM) {
            const float* Wb = (n < D) ? (Wk + (long)L * KVDIM * D)
                                      : (Wv + (long)L * KVDIM * D);
            int nn = (n < D) ? n : (n - D);
            v = Wb[(long)k * D + nn];
        } else if (k == KVDIM) {
            v = (n < D) ? bk[L * D + n] : bv[L * D + (n - D)];
        }
        unsigned short hi = f2bf(v);
        unsigned short lo = f2bf(v - bf2f(hi));
        bpack[(long)L * 196608 + rem]         = (short)hi;
        bpack[(long)L * 196608 + 98304 + rem] = (short)lo;
    } else if (gid < 2 * 98304 + 256) {
        int x = gid - 2 * 98304;
        int L = x >> 7, j = x & 127;
        float s = bq[L * D + j];
        for (int t = 0; t < DT; ++t)
            s += cosf(tb[L * DT + t]) * Wq[(long)L * QDIM * D + (D + t) * D + j];
        qc_ws[L * D + j] = s;
    }
}

// ---------------------------------------------------------------------------
// Kernel 3: q projection into q_out (which is the attn o-buffer: attn reads
// its block's q rows then overwrites them with o -- block-private, no hazard).
// ---------------------------------------------------------------------------
__global__ __launch_bounds__(256) void qdh_kernel(
    const float* __restrict__ dst_feat, const int* __restrict__ dst_nodes,
    const float* __restrict__ memory, const float* __restrict__ Wq,
    const float* __restrict__ qc, float* __restrict__ q_out)
{
    __shared__ float dh[4][D];
    const int tid = threadIdx.x, j = tid & 127, rg = tid >> 7;
    const int base = blockIdx.x * 4;
    for (int idx = tid; idx < 4 * D; idx += 256) {
        int r = idx >> 7, c = idx & 127;
        long row = base + r;
        dh[r][c] = dst_feat[row * D + c] + memory[(long)dst_nodes[row] * D + c];
    }
    __syncthreads();
    const int r0 = rg * 2;
    float a0 = qc[j], a1 = qc[j];
    for (int c = 0; c < D; ++c) {
        float wv = Wq[c * D + j];
        a0 += dh[r0][c] * wv;
        a1 += dh[r0 + 1][c] * wv;
    }
    q_out[(long)(base + r0) * D + j]     = a0;
    q_out[(long)(base + r0 + 1) * D + j] = a1;
}

// ---------------------------------------------------------------------------
// Kernel 4: MFMA attention core.  3 dst rows/block (30 kv rows + 2 pad),
// 512 threads = 8 waves (wave w owns 32 output cols).  Split-bf16 K/V GEMM
// with register-double-buffered B loads; bias folded into GEMM (k=356 row).
// q is read from io (written by qdh) and overwritten with o at the end.
// ---------------------------------------------------------------------------
#define AS 392                    // A row stride in shorts
#define A_BYTES (32 * AS * 2 * 2) // 50,176: hi plane + lo plane
#define ATTN_SMEM (A_BYTES + 1536 + 240 + 128 + 128)

__global__ __launch_bounds__(512, 4) void attn_mfma_kernel(
    const float* __restrict__ src_feat,   // N x F x D
    const int*   __restrict__ src_nodes,  // N x F
    const float* __restrict__ dst_ts,     // N
    const float* __restrict__ src_ts,     // N x F
    const float* __restrict__ edge_feat,  // N x F x DE
    const float* __restrict__ memory,     // NNODES x D
    const float* __restrict__ tw, const float* __restrict__ tb,
    const short* __restrict__ bpack,      // this layer's packed Wk|Wv|bias
    float* __restrict__ io)               // in: q rows; out: o rows
{
    __shared__ __align__(16) char smem[ATTN_SMEM];
    short* A_hi  = (short*)smem;                  // [32][AS]
    short* A_lo  = A_hi + 32 * AS;                // [32][AS]
    float* K_lds = (float*)smem;                  // [30][132] aliases A
    float* V_lds = K_lds + 30 * 132;              // [30][132]
    float* q_lds = (float*)(smem + A_BYTES);          // [3][128]
    float* sc    = (float*)(smem + A_BYTES + 1536);   // [3][2][10]
    int*   sn    = (int*)  (smem + A_BYTES + 1536 + 240); // [30]
    float* dts   = (float*)(smem + A_BYTES + 1536 + 240 + 128); // [30]

    const int tid  = threadIdx.x;
    const int base = blockIdx.x * 3;
    const long rbase = (long)base * FF;

    // P0: zero A (pads + lo of bias col), stage q, src_nodes, delta-ts
    {
        int4 z = {0, 0, 0, 0};
        int4* az = (int4*)smem;
        for (int i = tid; i < A_BYTES / 16; i += 512) az[i] = z;
    }
    if (tid < 3 * D) q_lds[tid] = io[(long)base * D + tid];
    if (tid < 30) {
        sn[tid]  = src_nodes[rbase + tid];
        dts[tid] = dst_ts[base + tid / FF] - src_ts[rbase + tid];
    }
    __syncthreads();

    // P1: build split-bf16 A tile (branch-free coalesced loops)
    for (int idx = tid; idx < 30 * 128; idx += 512) {
        int r = idx >> 7, c = idx & 127;
        float v = src_feat[(rbase + r) * D + c] + memory[(long)sn[r] * D + c];
        unsigned short h = f2bf(v);
        A_hi[r * AS + c] = (short)h;
        A_lo[r * AS + c] = (short)f2bf(v - bf2f(h));
    }
    for (int idx = tid; idx < 30 * 128; idx += 512) {
        int r = idx >> 7, c = idx & 127;
        float v = edge_feat[(rbase + r) * DE + c];
        unsigned short h = f2bf(v);
        A_hi[r * AS + 128 + c] = (short)h;
        A_lo[r * AS + 128 + c] = (short)f2bf(v - bf2f(h));
    }
    for (int idx = tid; idx < 30 * 100; idx += 512) {
        int r = idx / 100, tc = idx - r * 100;
        float v = cosf(dts[r] * tw[tc] + tb[tc]);
        unsigned short h = f2bf(v);
        A_hi[r * AS + 256 + tc] = (short)h;
        A_lo[r * AS + 256 + tc] = (short)f2bf(v - bf2f(h));
    }
    if (tid < 30) A_hi[tid * AS + 356] = (short)0x3F80;  // 1.0 (bias col)
    __syncthreads();

    // P2: GEMM [32x384]x[384x256] -> K|V (+bias), B reg-double-buffered
    const int l = tid & 63, w = tid >> 6;
    const int arow = l & 15, kgrp = l >> 4;
    const int nb = w * 2;                 // first of 2 n-tiles for this wave

    f32x4 acc[2][2] = {};
    const bf16x8* bpv = (const bf16x8*)bpack;

    bf16x8 hA0, hA1, lA0, lA1, hB0, hB1, lB0, lB1;
#define LOADB(kc, h0, h1, l0, l1) { \
    const bf16x8* bp = bpv + (((kc) * 16 + nb) * 64 + l); \
    h0 = bp[0]; h1 = bp[64]; l0 = bp[12288]; l1 = bp[12288 + 64]; }
#define AFRAG(kc) { \
    const short* pa = A_hi + arow * AS + (kc) * 32 + kgrp * 8; \
    ah0 = *(const bf16x8*)pa;            ah1 = *(const bf16x8*)(pa + 16 * AS); \
    al0 = *(const bf16x8*)(pa + 32 * AS); al1 = *(const bf16x8*)(pa + 48 * AS); }
#define MFMA3(mt, t, ah, al, bh, bl) { \
    acc[mt][t] = __builtin_amdgcn_mfma_f32_16x16x32_bf16(ah, bh, acc[mt][t], 0, 0, 0); \
    acc[mt][t] = __builtin_amdgcn_mfma_f32_16x16x32_bf16(ah, bl, acc[mt][t], 0, 0, 0); \
    acc[mt][t] = __builtin_amdgcn_mfma_f32_16x16x32_bf16(al, bh, acc[mt][t], 0, 0, 0); }

    LOADB(0, hA0, hA1, lA0, lA1);
    for (int kc = 0; kc < 12; kc += 2) {
        bf16x8 ah0, ah1, al0, al1;
        LOADB(kc + 1, hB0, hB1, lB0, lB1);
        AFRAG(kc);
        MFMA3(0, 0, ah0, al0, hA0, lA0);
        MFMA3(0, 1, ah0, al0, hA1, lA1);
        MFMA3(1, 0, ah1, al1, hA0, lA0);
        MFMA3(1, 1, ah1, al1, hA1, lA1);
        if (kc + 2 < 12) LOADB(kc + 2, hA0, hA1, lA0, lA1);
        AFRAG(kc + 1);
        MFMA3(0, 0, ah0, al0, hB0, lB0);
        MFMA3(0, 1, ah0, al0, hB1, lB1);
        MFMA3(1, 0, ah1, al1, hB0, lB0);
        MFMA3(1, 1, ah1, al1, hB1, lB1);
    }
#undef LOADB
#undef AFRAG
#undef MFMA3
    __syncthreads();   // all A reads complete; safe to alias with K/V

    // P3: scatter acc -> K/V LDS.  C/D: col=lane&15, row=(lane>>4)*4+reg
    #pragma unroll
    for (int mt = 0; mt < 2; ++mt) {
        #pragma unroll
        for (int t = 0; t < 2; ++t) {
            int col = (nb + t) * 16 + arow;
            #pragma unroll
            for (int r = 0; r < 4; ++r) {
                int row = mt * 16 + kgrp * 4 + r;
                if (row < 30) {
                    float v = acc[mt][t][r];
                    if (col < D) K_lds[row * 132 + col]       = v;
                    else         V_lds[row * 132 + (col - D)] = v;
                }
            }
        }
    }
    __syncthreads();

    // P4: scores: 60 (row,f,h) dots of 64
    if (tid < 60) {
        int row = tid / 20;
        int rem = tid - row * 20;
        int f = rem >> 1, h = rem & 1;
        const float* qp = q_lds + row * D + h * 64;
        const float* kp = K_lds + (row * FF + f) * 132 + h * 64;
        float s = 0.f;
        #pragma unroll
        for (int d = 0; d < 64; d += 4) {
            float4 qv = *(const float4*)(qp + d);
            float4 kv = *(const float4*)(kp + d);
            s += qv.x * kv.x + qv.y * kv.y + qv.z * kv.z + qv.w * kv.w;
        }
        sc[(row * 2 + h) * FF + f] = s * 0.125f;
    }
    __syncthreads();
    // P5: softmax
    if (tid < 6) {
        int r = tid >> 1, h = tid & 1;
        float* sp = sc + (r * 2 + h) * FF;
        float m = -1e30f;
        #pragma unroll
        for (int f = 0; f < FF; ++f) m = fmaxf(m, sp[f]);
        float sum = 0.f;
        #pragma unroll
        for (int f = 0; f < FF; ++f) { float e = expf(sp[f] - m); sp[f] = e; sum += e; }
        float inv = 1.f / sum;
        #pragma unroll
        for (int f = 0; f < FF; ++f) sp[f] *= inv;
    }
    __syncthreads();

    // P6: PV + write o over q rows
    for (int idx = tid; idx < 3 * D; idx += 512) {
        int row = idx >> 7, j = idx & 127;
        int h = j >> 6;
        const float* ap = sc + (row * 2 + h) * FF;
        float o = 0.f;
        #pragma unroll
        for (int f = 0; f < FF; ++f) o += ap[f] * V_lds[(row * FF + f) * 132 + j];
        io[(long)(base + row) * D + j] = o;
    }
}

// ---------------------------------------------------------------------------
// Kernel 5: fused layer-1 epilogue: one group g (10 rows) per block.
//   h = relu([dh|o] @ Wo1 + bo1); h_root1[g] = mean_f h; h1 = h @ e2nW + e2nb
// ---------------------------------------------------------------------------
__global__ __launch_bounds__(512) void post1_kernel(
    const float* __restrict__ dst_feat, const int* __restrict__ dst_nodes,
    const float* __restrict__ memory,
    const float* __restrict__ Wo, const float* __restrict__ bo,
    const float* __restrict__ e2nW, const float* __restrict__ e2nb,
    float* __restrict__ h1, float* __restrict__ h_root1)
{
    __shared__ float dh[12][D], oo[12][D], hh[12][D];
    const int tid = threadIdx.x;
    const int g = blockIdx.x;
    const long rb = (long)g * FF;

    for (int idx = tid; idx < 12 * D; idx += 512) {
        int r = idx >> 7, c = idx & 127;
        float dv = 0.f, ov = 0.f;
        if (r < FF) {
            long row = rb + r;
            dv = dst_feat[row * D + c] + memory[(long)dst_nodes[row] * D + c];
            ov = h1[row * D + c];
        }
        dh[r][c] = dv; oo[r][c] = ov;
    }
    __syncthreads();

    const int j = tid & 127, sub = tid >> 7;
    const int r0 = sub, r1 = sub + 4, r2 = sub + 8;
    float a0 = bo[j], a1 = a0, a2 = a0;
    for (int c = 0; c < D; ++c) {
        float wv = Wo[c * D + j];
        a0 += dh[r0][c] * wv; a1 += dh[r1][c] * wv; a2 += dh[r2][c] * wv;
    }
    for (int c = 0; c < D; ++c) {
        float wv = Wo[(D + c) * D + j];
        a0 += oo[r0][c] * wv; a1 += oo[r1][c] * wv; a2 += oo[r2][c] * wv;
    }
    hh[r0][j] = fmaxf(a0, 0.f);
    hh[r1][j] = fmaxf(a1, 0.f);
    hh[r2][j] = fmaxf(a2, 0.f);
    __syncthreads();

    if (sub == 0) {
        float s = 0.f;
        #pragma unroll
        for (int r = 0; r < FF; ++r) s += hh[r][j];
        h_root1[(long)g * D + j] = s * 0.1f;
    }
    float b0 = e2nb[j];
    a0 = b0; a1 = b0; a2 = b0;
    for (int c = 0; c < D; ++c) {
        float wv = e2nW[c * D + j];
        a0 += hh[r0][c] * wv; a1 += hh[r1][c] * wv; a2 += hh[r2][c] * wv;
    }
    h1[(rb + r0) * D + j] = a0;
    h1[(rb + r1) * D + j] = a1;
    if (r2 < FF) h1[(rb + r2) * D + j] = a2;
}

// ---------------------------------------------------------------------------
// Kernel 6: layer-0 output projection (4 rows/block), o in-place capable.
// ---------------------------------------------------------------------------
__global__ __launch_bounds__(256) void wo_kernel(
    const float* __restrict__ dst_feat, const int* __restrict__ dst_nodes,
    const float* __restrict__ memory,
    const float* __restrict__ o_in,
    const float* __restrict__ Wo, const float* __restrict__ bo,
    const float* __restrict__ add_in, float* __restrict__ out)
{
    __shared__ float dh[4][D], oo[4][D];
    const int tid = threadIdx.x, j = tid & 127, rg = tid >> 7;
    const int base = blockIdx.x * 4;
    for (int idx = tid; idx < 4 * D; idx += 256) {
        int r = idx >> 7, c = idx & 127;
        long row = base + r;
        dh[r][c] = dst_feat[row * D + c] + memory[(long)dst_nodes[row] * D + c];
        oo[r][c] = o_in[row * D + c];
    }
    __syncthreads();
    const int r0 = rg * 2;
    float a0 = bo[j], a1 = bo[j];
    for (int c = 0; c < D; ++c) {
        float wv = Wo[c * D + j];
        a0 += dh[r0][c] * wv;
        a1 += dh[r0 + 1][c] * wv;
    }
    for (int c = 0; c < D; ++c) {
        float wv = Wo[(D + c) * D + j];
        a0 += oo[r0][c] * wv;
        a1 += oo[r0 + 1][c] * wv;
    }
    long row = base + r0;
    float v0 = fmaxf(a0, 0.f), v1 = fmaxf(a1, 0.f);
    if (add_in) {
        v0 = (v0 + add_in[row * D + j]) * 0.5f;
        v1 = (v1 + add_in[(row + 1) * D + j]) * 0.5f;
    }
    out[row * D + j]       = v0;
    out[(row + 1) * D + j] = v1;
}

// ---------------------------------------------------------------------------
// Fallback scalar attention (verified 1774us pipeline), used if ws too small.
// ---------------------------------------------------------------------------
__global__ __launch_bounds__(256) void attn_fallback_kernel(
    int N,
    const float* __restrict__ dst_feat,
    const float* __restrict__ src_feat,
    const int*   __restrict__ dst_nodes,
    const int*   __restrict__ src_nodes,
    const float* __restrict__ dst_ts,
    const float* __restrict__ src_ts,
    const float* __restrict__ edge_feat,
    const float* __restrict__ memory,
    const float* __restrict__ Wq, const float* __restrict__ bq,
    const float* __restrict__ Wk, const float* __restrict__ bk,
    const float* __restrict__ Wv, const float* __restrict__ bv,
    const float* __restrict__ Wo, const float* __restrict__ bo,
    const float* __restrict__ tw, const float* __restrict__ tb,
    const float* __restrict__ add_in,
    float* __restrict__ out)
{
    __shared__ float kv_lds[4 * FF * KVDIM];
    __shared__ float dh_lds[4][D];
    __shared__ float qt_lds[DT];
    __shared__ float sc_lds[4][2][FF];
    __shared__ float o_lds[4][D];

    const int tid  = threadIdx.x;
    const int j    = tid & 127;
    const int rg   = tid >> 7;
    const int base = blockIdx.x * 4;
    const int head = j >> 6;

    if (tid < DT) qt_lds[tid] = cosf(tb[tid]);

    for (int idx = tid; idx < 4 * D; idx += 256) {
        int r = idx >> 7, c = idx & 127;
        int row = base + r;
        if (row < N)
            dh_lds[r][c] = dst_feat[(long)row * D + c] +
                           memory[(long)dst_nodes[row] * D + c];
    }
    for (int idx = tid; idx < 4 * FF * KVDIM; idx += 256) {
        int r   = idx / (FF * KVDIM);
        int rem = idx - r * (FF * KVDIM);
        int f   = rem / KVDIM;
        int c   = rem - f * KVDIM;
        int row = base + r;
        if (row >= N) continue;
        float val;
        if (c < D) {
            val = src_feat[((long)row * FF + f) * D + c] +
                  memory[(long)src_nodes[row * FF + f] * D + c];
        } else if (c < D + DE) {
            val = edge_feat[((long)row * FF + f) * DE + (c - D)];
        } else {
            float dt_ = dst_ts[row] - src_ts[row * FF + f];
            int tc = c - (D + DE);
            val = cosf(dt_ * tw[tc] + tb[tc]);
        }
        kv_lds[idx] = val;
    }
    __syncthreads();

    const int r0 = rg * 2;
    float q0 = bq[j], q1 = bq[j];
    for (int c = 0; c < D; ++c) {
        float wq = Wq[c * D + j];
        q0 += dh_lds[r0][c] * wq;
        q1 += dh_lds[r0 + 1][c] * wq;
    }
    {
        float qadd = 0.f;
        for (int c = 0; c < DT; ++c) qadd += qt_lds[c] * Wq[(D + c) * D + j];
        q0 += qadd; q1 += qadd;
    }

    float acc_k[2][FF], acc_v[2][FF];
    #pragma unroll
    for (int r2 = 0; r2 < 2; ++r2)
        #pragma unroll
        for (int f = 0; f < FF; ++f) { acc_k[r2][f] = 0.f; acc_v[r2][f] = 0.f; }

    for (int c = 0; c < KVDIM; c += 4) {
        float wk0 = Wk[(c + 0) * D + j], wk1 = Wk[(c + 1) * D + j];
        float wk2 = Wk[(c + 2) * D + j], wk3 = Wk[(c + 3) * D + j];
        float wv0 = Wv[(c + 0) * D + j], wv1 = Wv[(c + 1) * D + j];
        float wv2 = Wv[(c + 2) * D + j], wv3 = Wv[(c + 3) * D + j];
        #pragma unroll
        for (int r2 = 0; r2 < 2; ++r2) {
            #pragma unroll
            for (int f = 0; f < FF; ++f) {
                const float4 kvv = *(const float4*)&kv_lds[((r0 + r2) * FF + f) * KVDIM + c];
                acc_k[r2][f] += kvv.x * wk0 + kvv.y * wk1 + kvv.z * wk2 + kvv.w * wk3;
                acc_v[r2][f] += kvv.x * wv0 + kvv.y * wv1 + kvv.z * wv2 + kvv.w * wv3;
            }
        }
    }

    const float bkj = bk[j], bvj = bv[j];
    const float qv[2] = {q0, q1};

    #pragma unroll
    for (int r2 = 0; r2 < 2; ++r2) {
        #pragma unroll
        for (int f = 0; f < FF; ++f) {
            float val = qv[r2] * (acc_k[r2][f] + bkj);
            for (int off = 32; off > 0; off >>= 1) val += __shfl_xor(val, off, 64);
            if ((tid & 63) == 0) sc_lds[r0 + r2][head][f] = val;
        }
    }
    __syncthreads();

    if (tid < 8) {
        int r = tid >> 1, h = tid & 1;
        float s[FF], m = -1e30f;
        #pragma unroll
        for (int f = 0; f < FF; ++f) { s[f] = sc_lds[r][h][f] * 0.125f; m = fmaxf(m, s[f]); }
        float sum = 0.f;
        #pragma unroll
        for (int f = 0; f < FF; ++f) { s[f] = expf(s[f] - m); sum += s[f]; }
        float inv = 1.f / sum;
        #pragma unroll
        for (int f = 0; f < FF; ++f) sc_lds[r][h][f] = s[f] * inv;
    }
    __syncthreads();

    #pragma unroll
    for (int r2 = 0; r2 < 2; ++r2) {
        float o = 0.f;
        #pragma unroll
        for (int f = 0; f < FF; ++f) o += sc_lds[r0 + r2][head][f] * (acc_v[r2][f] + bvj);
        o_lds[r0 + r2][j] = o;
    }
    __syncthreads();

    float a0 = bo[j], a1 = bo[j];
    for (int c = 0; c < D; ++c) {
        float w = Wo[c * D + j];
        a0 += dh_lds[r0][c] * w;
        a1 += dh_lds[r0 + 1][c] * w;
    }
    for (int c = 0; c < D; ++c) {
        float w = Wo[(D + c) * D + j];
        a0 += o_lds[r0][c] * w;
        a1 += o_lds[r0 + 1][c] * w;
    }
    {
        int row = base + r0;
        if (row < N) {
            float v = fmaxf(a0, 0.f);
            if (add_in) v = (v + add_in[(long)row * D + j]) * 0.5f;
            out[(long)row * D + j] = v;
        }
        row = base + r0 + 1;
        if (row < N) {
            float v = fmaxf(a1, 0.f);
            if (add_in) v = (v + add_in[(long)row * D + j]) * 0.5f;
            out[(long)row * D + j] = v;
        }
    }
}

// ---------------------------------------------------------------------------
// Fallback-path helpers (hroot / e2n)
// ---------------------------------------------------------------------------
__global__ void hroot_kernel(const float* __restrict__ h1, float* __restrict__ out) {
    int idx = blockIdx.x * blockDim.x + threadIdx.x;
    if (idx >= GG * D) return;
    int g = idx >> 7, d = idx & 127;
    float s = 0.f;
    #pragma unroll
    for (int f = 0; f < FF; ++f) s += h1[(long)(g * FF + f) * D + d];
    out[idx] = s / 10.0f;
}

__global__ __launch_bounds__(256) void e2n_kernel(
    float* __restrict__ h1, const float* __restrict__ W, const float* __restrict__ b) {
    __shared__ float h_lds[4][D];
    const int tid = threadIdx.x, j = tid & 127, rg = tid >> 7;
    const int base = blockIdx.x * 4;
    for (int idx = tid; idx < 4 * D; idx += 256)
        h_lds[idx >> 7][idx & 127] = h1[(long)(base + (idx >> 7)) * D + (idx & 127)];
    __syncthreads();
    float a0 = b[j], a1 = b[j];
    const int r0 = rg * 2;
    for (int c = 0; c < D; ++c) {
        float w = W[c * D + j];
        a0 += h_lds[r0][c] * w;
        a1 += h_lds[r0 + 1][c] * w;
    }
    h1[(long)(base + r0) * D + j]     = a0;
    h1[(long)(base + r0 + 1) * D + j] = a1;
}

// ---------------------------------------------------------------------------
// Kernel: GRU memory update (1024 rows), 2 rows/block, 384 threads
// ---------------------------------------------------------------------------
__global__ __launch_bounds__(384) void gru_kernel(
    const int*   __restrict__ dst_nodes0,
    const float* __restrict__ root_ts,
    const float* __restrict__ root_edge_feat,
    const float* __restrict__ memory,
    const float* __restrict__ memory_ts,
    const float* __restrict__ h_total,
    const float* __restrict__ mt_w, const float* __restrict__ mt_b,
    const float* __restrict__ Wih,  const float* __restrict__ Whh,
    const float* __restrict__ bih,  const float* __restrict__ bhh,
    float* __restrict__ new_mem)
{
    __shared__ float x_lds[2][484];
    __shared__ float gi_lds[2][384];
    __shared__ float gh_lds[2][384];
    const int tid = threadIdx.x;
    const int base = blockIdx.x * 2;

    for (int idx = tid; idx < 2 * 484; idx += 384) {
        int r = idx / 484, c = idx - r * 484;
        int row = base + r;
        int node = dst_nodes0[row];
        float v;
        if (c < 128)      v = h_total[(long)row * D + c];
        else if (c < 256) v = memory[(long)node * D + (c - 128)];
        else if (c < 356) {
            float dt_ = fmaxf(root_ts[row & 511] - memory_ts[node], 0.f);
            v = cosf(dt_ * mt_w[c - 256] + mt_b[c - 256]);
        } else            v = root_edge_feat[(long)(row & 511) * DE + (c - 356)];
        x_lds[r][c] = v;
    }
    __syncthreads();

    {
        float g0 = bih[tid], g1 = bih[tid];
        for (int c = 0; c < 484; ++c) {
            float w = Wih[c * 384 + tid];
            g0 += x_lds[0][c] * w;
            g1 += x_lds[1][c] * w;
        }
        gi_lds[0][tid] = g0; gi_lds[1][tid] = g1;
        float h0 = bhh[tid], h1_ = bhh[tid];
        for (int c = 0; c < 128; ++c) {
            float w = Whh[c * 384 + tid];
            h0  += x_lds[0][128 + c] * w;
            h1_ += x_lds[1][128 + c] * w;
        }
        gh_lds[0][tid] = h0; gh_lds[1][tid] = h1_;
    }
    __syncthreads();

    if (tid < 256) {
        int r = tid >> 7, d = tid & 127;
        float ir = gi_lds[r][d], iz = gi_lds[r][128 + d], in_ = gi_lds[r][256 + d];
        float hr = gh_lds[r][d], hz = gh_lds[r][128 + d], hn  = gh_lds[r][256 + d];
        float rr = 1.f / (1.f + expf(-(ir + hr)));
        float zz = 1.f / (1.f + expf(-(iz + hz)));
        float nn = tanhf(in_ + rr * hn);
        float h  = x_lds[r][128 + d];
        new_mem[(long)(base + r) * D + d] = (1.f - zz) * nn + zz * h;
    }
}

// ---------------------------------------------------------------------------
// Kernel: scatter new_mem into out_mem with last-occurrence-wins
// ---------------------------------------------------------------------------
__global__ __launch_bounds__(128) void scatter_kernel(
    const int*   __restrict__ dst_nodes0,
    const float* __restrict__ root_ts,
    const float* __restrict__ new_mem,
    float* __restrict__ out_mem,
    float* __restrict__ out_ts)
{
    __shared__ int lose;
    const int i = blockIdx.x;     // 0..1023
    const int tid = threadIdx.x;
    if (tid == 0) lose = 0;
    __syncthreads();
    const int node = dst_nodes0[i];
    for (int jj = i + 1 + tid; jj < 1024; jj += 128)
        if (dst_nodes0[jj] == node) lose = 1;
    __syncthreads();
    if (!lose) {
        out_mem[(long)node * D + tid] = new_mem[(long)i * D + tid];
        if (tid == 0) out_ts[node] = root_ts[i & 511];
    }
}

// ---------------------------------------------------------------------------
// Kernel: edge predictor, 4 rows/block, 128 threads
// ---------------------------------------------------------------------------
__global__ __launch_bounds__(128) void ep_kernel(
    const float* __restrict__ h_total,
    const float* __restrict__ Wsrc, const float* __restrict__ bsrc,
    const float* __restrict__ Wdst, const float* __restrict__ bdst,
    const float* __restrict__ Wout, const float* __restrict__ bout,
    float* __restrict__ out_pos, float* __restrict__ out_neg)
{
    __shared__ float hs[4][D], hd[4][D], hn[4][D];
    __shared__ float part[4][2][2];
    const int tid = threadIdx.x;
    const int base = blockIdx.x * 4;
    for (int idx = tid; idx < 4 * D; idx += 128) {
        int r = idx >> 7, c = idx & 127;
        hs[r][c] = h_total[(long)(base + r) * D + c];
        hd[r][c] = h_total[(long)(512 + base + r) * D + c];
        hn[r][c] = h_total[(long)(1024 + base + r) * D + c];
    }
    __syncthreads();
    const int j = tid;
    const float wout = Wout[j];
    for (int r = 0; r < 4; ++r) {
        float s = bsrc[j], dp = bdst[j], dn = bdst[j];
        for (int c = 0; c < D; ++c) {
            float ws = Wsrc[c * D + j], wd = Wdst[c * D + j];
            s  += hs[r][c] * ws;
            dp += hd[r][c] * wd;
            dn += hn[r][c] * wd;
        }
        float pv = fmaxf(s + dp, 0.f) * wout;
        float nv = fmaxf(s + dn, 0.f) * wout;
        for (int off = 32; off > 0; off >>= 1) {
            pv += __shfl_xor(pv, off, 64);
            nv += __shfl_xor(nv, off, 64);
        }
        if ((tid & 63) == 0) { part[r][0][tid >> 6] = pv; part[r][1][tid >> 6] = nv; }
    }
    __syncthreads();
    if (tid < 4) {
        out_pos[base + tid] = part[tid][0][0] + part[tid][0][1] + bout[0];
        out_neg[base + tid] = part[tid][1][0] + part[tid][1][1] + bout[0];
    }
}

// ---------------------------------------------------------------------------
extern "C" void kernel_launch(void* const* d_in, const int* in_sizes, int n_in,
                              void* d_out, int out_size, void* d_ws, size_t ws_size,
                              hipStream_t stream) {
    const int*   dst_nodes0     = (const int*)d_in[0];
    const int*   src_nodes0     = (const int*)d_in[1];
    const float* dst_feat0      = (const float*)d_in[2];
    const float* dst_ts0        = (const float*)d_in[3];
    const float* src_ts0        = (const float*)d_in[4];
    const float* edge_feat0     = (const float*)d_in[5];
    const int*   dst_nodes1     = (const int*)d_in[6];
    const int*   src_nodes1     = (const int*)d_in[7];
    const float* dst_feat1      = (const float*)d_in[8];
    const float* src_feat1      = (const float*)d_in[9];
    const float* dst_ts1        = (const float*)d_in[10];
    const float* src_ts1        = (const float*)d_in[11];
    const float* edge_feat1     = (const float*)d_in[12];
    const float* root_ts        = (const float*)d_in[13];
    const float* root_edge_feat = (const float*)d_in[14];
    const float* memory         = (const float*)d_in[15];
    const float* memory_ts      = (const float*)d_in[16];
    const float* Wq  = (const float*)d_in[17];
    const float* bq  = (const float*)d_in[18];
    const float* Wk  = (const float*)d_in[19];
    const float* bk  = (const float*)d_in[20];
    const float* Wv  = (const float*)d_in[21];
    const float* bv  = (const float*)d_in[22];
    const float* Wo  = (const float*)d_in[23];
    const float* bo  = (const float*)d_in[24];
    const float* tw  = (const float*)d_in[25];
    const float* tb  = (const float*)d_in[26];
    const float* e2n_W = (const float*)d_in[27];
    const float* e2n_b = (const float*)d_in[28];
    const float* mt_w  = (const float*)d_in[29];
    const float* mt_b  = (const float*)d_in[30];
    const float* gru_Wih = (const float*)d_in[31];
    const float* gru_Whh = (const float*)d_in[32];
    const float* gru_bih = (const float*)d_in[33];
    const float* gru_bhh = (const float*)d_in[34];
    const float* ep_Wsrc = (const float*)d_in[35];
    const float* ep_bsrc = (const float*)d_in[36];
    const float* ep_Wdst = (const float*)d_in[37];
    const float* ep_bdst = (const float*)d_in[38];
    const float* ep_Wout = (const float*)d_in[39];
    const float* ep_bout = (const float*)d_in[40];

    float* out     = (float*)d_out;
    float* out_pos = out;
    float* out_neg = out + 512;
    float* out_mem = out + 1024;
    float* out_ts  = out + 1024 + (long)NNODES * D;

    float* ws       = (float*)d_ws;
    float* h1       = ws;                          // NN1*D (q -> o -> h -> next_src)
    float* h_root1  = h1 + (long)NN1 * D;          // GG*D
    float* h_total  = h_root1 + (long)GG * D;      // GG*D (q -> o -> h_total)
    float* new_mem  = h_total + (long)GG * D;      // 1024*D
    float* qc_ws    = new_mem + 1024L * D;         // 2*D
    short* bpack    = (short*)(qc_ws + 256);       // 2*196608 shorts (786,432 B)

    const size_t REQ_MFMA = (size_t)((long)(NN1 + 2 * GG + 1024) * D + 256) * 4
                          + 2 * 196608 * sizeof(short);   // 10,748,928
    const bool use_mfma = (ws_size == 0) || (ws_size >= REQ_MFMA);

    // 1. bulk copy memory/memory_ts -> out (scatter overwrites updated rows)
    copy_kernel<<<4096, 256, 0, stream>>>((const float4*)memory, (const float4*)memory_ts,
                                          (float4*)out_mem, (float4*)out_ts);

    if (use_mfma) {
        // 2. prepack split-bf16 weights (+bias row) + qconst
        prepack_kernel<<<769, 256, 0, stream>>>(Wk, Wv, Wq, bq, bk, bv, tb, bpack, qc_ws);
        // 3. layer-1 q -> h1
        qdh_kernel<<<NN1 / 4, 256, 0, stream>>>(dst_feat1, dst_nodes1, memory,
                                                Wq + QDIM * D, qc_ws + D, h1);
        // 4. layer-1 attention core (reads q from h1, writes o to h1)
        attn_mfma_kernel<<<NN1 / 3, 512, 0, stream>>>(
            src_feat1, src_nodes1, dst_ts1, src_ts1, edge_feat1, memory,
            tw + DT, tb + DT, bpack + 196608, h1);
        // 5. fused Wo1 + h_root1 + e2n (h1 in-place -> next_src)
        post1_kernel<<<GG, 512, 0, stream>>>(dst_feat1, dst_nodes1, memory,
                                             Wo + 2 * D * D, bo + D, e2n_W, e2n_b,
                                             h1, h_root1);
        // 6. layer-0 q -> h_total
        qdh_kernel<<<GG / 4, 256, 0, stream>>>(dst_feat0, dst_nodes0, memory,
                                               Wq, qc_ws, h_total);
        // 7. layer-0 attention core (src = next_src in h1; q/o in h_total)
        attn_mfma_kernel<<<GG / 3, 512, 0, stream>>>(
            h1, src_nodes0, dst_ts0, src_ts0, edge_feat0, memory,
            tw, tb, bpack, h_total);
        // 8. layer-0 output projection, in-place, fused (x + h_root1)/2
        wo_kernel<<<GG / 4, 256, 0, stream>>>(dst_feat0, dst_nodes0, memory,
                                              h_total, Wo, bo, h_root1, h_total);
    } else {
        attn_fallback_kernel<<<NN1 / 4, 256, 0, stream>>>(
            NN1, dst_feat1, src_feat1, dst_nodes1, src_nodes1, dst_ts1, src_ts1,
            edge_feat1, memory,
            Wq + QDIM * D, bq + D, Wk + KVDIM * D, bk + D, Wv + KVDIM * D, bv + D,
            Wo + 2 * D * D, bo + D, tw + DT, tb + DT, nullptr, h1);
        hroot_kernel<<<(GG * D + 255) / 256, 256, 0, stream>>>(h1, h_root1);
        e2n_kernel<<<NN1 / 4, 256, 0, stream>>>(h1, e2n_W, e2n_b);
        attn_fallback_kernel<<<GG / 4, 256, 0, stream>>>(
            GG, dst_feat0, h1, dst_nodes0, src_nodes0, dst_ts0, src_ts0, edge_feat0,
            memory, Wq, bq, Wk, bk, Wv, bv, Wo, bo, tw, tb, h_root1, h_total);
    }

    // 9. GRU memory update
    gru_kernel<<<512, 384, 0, stream>>>(dst_nodes0, root_ts, root_edge_feat, memory,
                                        memory_ts, h_total, mt_w, mt_b,
                                        gru_Wih, gru_Whh, gru_bih, gru_bhh, new_mem);
    // 10. scatter (last-occurrence-wins)
    scatter_kernel<<<1024, 128, 0, stream>>>(dst_nodes0, root_ts, new_mem, out_mem, out_ts);
    // 11. edge predictor
    ep_kernel<<<BB / 4, 128, 0, stream>>>(h_total, ep_Wsrc, ep_bsrc, ep_Wdst, ep_bdst,
                                          ep_Wout, ep_bout, out_pos, out_neg);
}